// Round 3
// baseline (6141.727 us; speedup 1.0000x reference)
//
#include <hip/hip_runtime.h>
#include <cstdint>
#include <cmath>

#define Bn 64
#define Tn 512
#define Dn 1024
#define Hn 1024

typedef __attribute__((ext_vector_type(8))) short short8;
typedef __attribute__((ext_vector_type(8))) __bf16 bf16x8;
typedef __attribute__((ext_vector_type(16))) float floatx16;
typedef __attribute__((ext_vector_type(2))) unsigned long long ull2;

__device__ __forceinline__ short f2bf(float f) {
    unsigned u = __float_as_uint(f);
    unsigned r = (u + 0x7FFFu + ((u >> 16) & 1u)) >> 16;
    return (short)(r & 0xFFFFu);
}

// Convert x [B][T][D] fp32 -> xb [T][B][D] bf16 (time-major for per-step locality)
__global__ void convert_x_kernel(const float* __restrict__ x, short* __restrict__ xb) {
    size_t idx = ((size_t)blockIdx.x * blockDim.x + threadIdx.x) * 8;
    size_t b = idx >> 19;              // T*D = 2^19
    size_t r = idx & ((1u << 19) - 1);
    size_t t = r >> 10;                // D = 2^10
    size_t d = r & 1023;
    const float* src = x + idx;
    short8 o;
#pragma unroll
    for (int j = 0; j < 8; ++j) o[j] = f2bf(src[j]);
    *(short8*)(xb + ((t * Bn + b) << 10) + d) = o;
}

// Init h buffer 0 from h0 (bf16) and zero the barrier slot array (64 KB)
__global__ void prep_kernel(const float* __restrict__ h0, short* __restrict__ hb,
                            unsigned* __restrict__ slots) {
    int i = blockIdx.x * blockDim.x + threadIdx.x;   // 0..65535
    hb[i] = f2bf(h0[i]);                              // B*H = 65536
    if (i < 16384) slots[i] = 0;                      // 2 groups * 128 slots * 64 u32
}

// MODE 0: full per-step h buffers (never-reused lines -> plain cached reads) + bf16 x
// MODE 1: ping-pong h buffers, agent-scope atomic h reads + bf16 x
// MODE 2: like 1 but x read as fp32 directly (tiny-ws fallback)
template <int MODE>
__global__ __launch_bounds__(256, 1)
void lstm_kernel(const float* __restrict__ x, const short* __restrict__ xb,
                 const float* __restrict__ c0,
                 const float* __restrict__ Wfx, const float* __restrict__ bf_, const float* __restrict__ Wfh,
                 const float* __restrict__ Wix, const float* __restrict__ bi_, const float* __restrict__ Wih,
                 const float* __restrict__ Wox, const float* __restrict__ bo_, const float* __restrict__ Woh,
                 const float* __restrict__ Wcx, const float* __restrict__ bc_, const float* __restrict__ Wch,
                 short* __restrict__ hbb, unsigned* __restrict__ slots,
                 float* __restrict__ out) {
    constexpr bool FULL = (MODE == 0);
    constexpr bool XB = (MODE <= 1);
    // WS=2066 shorts -> 1033 dwords = 9 (mod 32): b128 weight reads are 2-way (free)
    constexpr int WS = 2066;
    constexpr int BH = Bn * Hn;              // 65536 shorts per h buffer
    __shared__ short Wlds[32 * WS];          // 132224 B
    __shared__ float Gs[4][32][33];          // 16896 B: [wave][col][row(batch)]

    const int tid = threadIdx.x;
    const int blk = blockIdx.x;
    const int group = blk >> 7;              // 0..1 (32 batches each)
    const int bIG = blk & 127;               // block in group
    const int u0 = bIG * 8;                  // 8 hidden units per block

    // ---- stage weight slices into LDS (fp32 global -> bf16 LDS) ----
    {
        const int col = tid & 31;            // 0..31 = gate*8 + u
        const int kr0 = tid >> 5;            // 0..7
        const int gate = col >> 3;
        const int uu = col & 7;
        const float* Wxm = (gate == 0) ? Wfx : (gate == 1) ? Wix : (gate == 2) ? Wox : Wcx;
        const float* Whm = (gate == 0) ? Wfh : (gate == 1) ? Wih : (gate == 2) ? Woh : Wch;
        for (int k = kr0; k < 1024; k += 8) {
            Wlds[col * WS + k]        = f2bf(Wxm[(size_t)k * Hn + u0 + uu]);
            Wlds[col * WS + 1024 + k] = f2bf(Whm[(size_t)k * Hn + u0 + uu]);
        }
    }

    // ---- epilogue-role state: thread owns (batch b_loc, unit uu2) ----
    const int b_loc = tid >> 3;              // 0..31
    const int uu2 = tid & 7;                 // 0..7
    const int bglob_e = group * 32 + b_loc;
    float c_state = c0[(size_t)bglob_e * Hn + u0 + uu2];
    const float bfv = bf_[u0 + uu2], biv = bi_[u0 + uu2];
    const float bov = bo_[u0 + uu2], bcv = bc_[u0 + uu2];
    float* outp = out + (size_t)bglob_e * Tn * Hn + u0 + uu2;

    // ---- MFMA-role constants: wave w covers K-slice [w*512, w*512+512) of (x|h) ----
    const int w = tid >> 6;
    const int lane = tid & 63;
    const int nm = lane & 31;                // m (batch) for A, n (col) for B
    const int half = lane >> 5;              // k sub-block
    const int src = w >> 1;                  // 0 = x, 1 = h
    const int kh = w & 1;                    // k-half within source
    const short* bfrag_base = &Wlds[nm * WS + src * 1024 + kh * 512 + half * 8];
    const int kofs = kh * 512 + half * 8;
    const int bglob_a = group * 32 + nm;

    unsigned* myslots = slots + group * 128 * 64;  // 256B-spaced slots
    unsigned* myslot = myslots + bIG * 64;

    // x A-fragments live in registers across the barrier (pipelined prefetch)
    bf16x8 afrag[32];
    if (XB && src == 0) {
        const short* A0 = xb + (((size_t)0 * Bn + bglob_a) << 10) + kofs;
#pragma unroll
        for (int j = 0; j < 32; ++j) afrag[j] = *(const bf16x8*)(const void*)(A0 + j * 16);
    }

    __syncthreads();

    for (int t = 0; t < Tn; ++t) {
        // ---- h-wave-only poll: wave-local __all, no block barrier, no vmcnt drain ----
        int dep = 0;
        if (src == 1 && t > 0) {
            unsigned v0, v1;
            for (;;) {
                v0 = __hip_atomic_load(myslots + (size_t)lane * 64, __ATOMIC_RELAXED,
                                       __HIP_MEMORY_SCOPE_AGENT);
                v1 = __hip_atomic_load(myslots + (size_t)(lane + 64) * 64, __ATOMIC_RELAXED,
                                       __HIP_MEMORY_SCOPE_AGENT);
                if (__all((v0 >= (unsigned)t) && (v1 >= (unsigned)t))) break;
                __builtin_amdgcn_s_sleep(1);
            }
            dep = (int)((v0 | v1) >> 16);   // always 0; defeats hoisting h loads above poll
        }

        floatx16 acc0, acc1;
#pragma unroll
        for (int r_ = 0; r_ < 16; ++r_) { acc0[r_] = 0.f; acc1[r_] = 0.f; }

        if (XB && src == 0) {
#pragma unroll
            for (int j = 0; j < 32; j += 2) {
                bf16x8 b0 = *(const bf16x8*)(const void*)(bfrag_base + j * 16);
                bf16x8 b1 = *(const bf16x8*)(const void*)(bfrag_base + j * 16 + 16);
                acc0 = __builtin_amdgcn_mfma_f32_32x32x16_bf16(afrag[j], b0, acc0, 0, 0, 0);
                acc1 = __builtin_amdgcn_mfma_f32_32x32x16_bf16(afrag[j + 1], b1, acc1, 0, 0, 0);
            }
        } else if (src == 1) {
            if (FULL) {
                const short* Ab = hbb + (size_t)t * BH + ((size_t)bglob_a << 10) + kofs + dep;
#pragma unroll
                for (int j = 0; j < 32; j += 2) {
                    bf16x8 a0 = *(const bf16x8*)(const void*)(Ab + j * 16);
                    bf16x8 b0 = *(const bf16x8*)(const void*)(bfrag_base + j * 16);
                    bf16x8 a1 = *(const bf16x8*)(const void*)(Ab + j * 16 + 16);
                    bf16x8 b1 = *(const bf16x8*)(const void*)(bfrag_base + j * 16 + 16);
                    acc0 = __builtin_amdgcn_mfma_f32_32x32x16_bf16(a0, b0, acc0, 0, 0, 0);
                    acc1 = __builtin_amdgcn_mfma_f32_32x32x16_bf16(a1, b1, acc1, 0, 0, 0);
                }
            } else {
                const unsigned long long* Ab64 = (const unsigned long long*)
                    (hbb + (size_t)(t & 1) * BH + ((size_t)bglob_a << 10) + kofs + dep);
#pragma unroll
                for (int j = 0; j < 32; ++j) {
                    ull2 q;
                    q[0] = __hip_atomic_load(Ab64 + j * 4, __ATOMIC_RELAXED, __HIP_MEMORY_SCOPE_AGENT);
                    q[1] = __hip_atomic_load(Ab64 + j * 4 + 1, __ATOMIC_RELAXED, __HIP_MEMORY_SCOPE_AGENT);
                    bf16x8 a = __builtin_bit_cast(bf16x8, q);
                    bf16x8 b0 = *(const bf16x8*)(const void*)(bfrag_base + j * 16);
                    if (j & 1) acc1 = __builtin_amdgcn_mfma_f32_32x32x16_bf16(a, b0, acc1, 0, 0, 0);
                    else       acc0 = __builtin_amdgcn_mfma_f32_32x32x16_bf16(a, b0, acc0, 0, 0, 0);
                }
            }
        } else {
            // MODE2: read fp32 x directly and convert in-register
            const float* Af = x + ((size_t)bglob_a * Tn + t) * Dn + kofs;
#pragma unroll
            for (int ks = 0; ks < 32; ++ks) {
                short8 tmp;
#pragma unroll
                for (int j = 0; j < 8; ++j) tmp[j] = f2bf(Af[ks * 16 + j]);
                bf16x8 a = __builtin_bit_cast(bf16x8, tmp);
                bf16x8 b0 = *(const bf16x8*)(const void*)(bfrag_base + ks * 16);
                if (ks & 1) acc1 = __builtin_amdgcn_mfma_f32_32x32x16_bf16(a, b0, acc1, 0, 0, 0);
                else        acc0 = __builtin_amdgcn_mfma_f32_32x32x16_bf16(a, b0, acc0, 0, 0, 0);
            }
        }

        // write partial sums: C/D layout col=lane&31, row=(reg&3)+8*(reg>>2)+4*(lane>>5)
#pragma unroll
        for (int r_ = 0; r_ < 16; ++r_) {
            int row = (r_ & 3) + 8 * (r_ >> 2) + 4 * half;
            Gs[w][nm][row] = acc0[r_] + acc1[r_];
        }
        __syncthreads();   // sync1: Gs write -> read

        // ---- epilogue: gates in fp32 ----
        float zf = Gs[0][uu2][b_loc] + Gs[1][uu2][b_loc] + Gs[2][uu2][b_loc] + Gs[3][uu2][b_loc] + bfv;
        float zi = Gs[0][8 + uu2][b_loc] + Gs[1][8 + uu2][b_loc] + Gs[2][8 + uu2][b_loc] + Gs[3][8 + uu2][b_loc] + biv;
        float zo = Gs[0][16 + uu2][b_loc] + Gs[1][16 + uu2][b_loc] + Gs[2][16 + uu2][b_loc] + Gs[3][16 + uu2][b_loc] + bov;
        float zc = Gs[0][24 + uu2][b_loc] + Gs[1][24 + uu2][b_loc] + Gs[2][24 + uu2][b_loc] + Gs[3][24 + uu2][b_loc] + bcv;
        float fg = fminf(fmaxf(fmaf(0.2f, zf, 0.5f), 0.f), 1.f);
        float ig = fminf(fmaxf(fmaf(0.2f, zi, 0.5f), 0.f), 1.f);
        float og = fminf(fmaxf(fmaf(0.2f, zo, 0.5f), 0.f), 1.f);
        float ct = tanhf(zc);
        c_state = fg * c_state + ig * ct;
        float hv = og * tanhf(c_state);

        // ---- h store FIRST (it is the inter-block dependency) ----
        {
            unsigned hv32 = (unsigned short)f2bf(hv);
            unsigned part = (unsigned)__shfl_xor((int)hv32, 1);
            if (!(tid & 1)) {
                unsigned packed = hv32 | (part << 16);
                size_t bofs = FULL ? (size_t)(t + 1) * BH : (size_t)((t + 1) & 1) * BH;
                __hip_atomic_store((unsigned*)(hbb + bofs + ((size_t)bglob_e << 10) + u0 + uu2),
                                   packed, __ATOMIC_RELAXED, __HIP_MEMORY_SCOPE_AGENT);
            }
        }

        __syncthreads();   // sync2: drains h stores (per-wave vmcnt(0)) + Gs reuse ordering

        // ---- release ASAP; everything after is off the critical path ----
        if (t < Tn - 1 && tid == 0)
            __hip_atomic_store(myslot, (unsigned)(t + 1), __ATOMIC_RELEASE,
                               __HIP_MEMORY_SCOPE_AGENT);

        outp[(size_t)t * Hn] = hv;   // out store overlaps next step

        // next-step x fragments: loads stay in flight while h-waves spin
        if (XB && src == 0 && t < Tn - 1) {
            const short* An = xb + (((size_t)(t + 1) * Bn + bglob_a) << 10) + kofs;
#pragma unroll
            for (int j = 0; j < 32; ++j) afrag[j] = *(const bf16x8*)(const void*)(An + j * 16);
        }
    }
}

extern "C" void kernel_launch(void* const* d_in, const int* in_sizes, int n_in,
                              void* d_out, int out_size, void* d_ws, size_t ws_size,
                              hipStream_t stream) {
    const float* x   = (const float*)d_in[0];
    const float* c0  = (const float*)d_in[1];
    const float* h0  = (const float*)d_in[2];
    const float* Wfx = (const float*)d_in[3];
    const float* bf_ = (const float*)d_in[4];
    const float* Wfh = (const float*)d_in[5];
    const float* Wix = (const float*)d_in[6];
    const float* bi_ = (const float*)d_in[7];
    const float* Wih = (const float*)d_in[8];
    const float* Wox = (const float*)d_in[9];
    const float* bo_ = (const float*)d_in[10];
    const float* Woh = (const float*)d_in[11];
    const float* Wcx = (const float*)d_in[12];
    const float* bc_ = (const float*)d_in[13];
    const float* Wch = (const float*)d_in[14];
    (void)in_sizes; (void)n_in; (void)out_size;
    float* out = (float*)d_out;

    char* ws = (char*)d_ws;
    unsigned* slots = (unsigned*)ws;                         // [0, 64 KB)
    const size_t xb_bytes = (size_t)Tn * Bn * Dn * 2;        // 64 MB

    const size_t off_hb = 1u << 20;                          // 1 MB
    const size_t off_xb_full = (70u << 20);
    const size_t need_full = off_xb_full + xb_bytes;         // ~134 MB
    const size_t off_xb_ping = 1u << 20;
    const size_t off_hb_ping = 64u << 10;
    const size_t need_ping = off_xb_ping + xb_bytes;         // ~65 MB

    if (ws_size >= need_full) {
        short* hbb = (short*)(ws + off_hb);
        short* xb  = (short*)(ws + off_xb_full);
        convert_x_kernel<<<(Tn * Bn * Dn / 8) / 256, 256, 0, stream>>>(x, xb);
        prep_kernel<<<256, 256, 0, stream>>>(h0, hbb, slots);
        lstm_kernel<0><<<256, 256, 0, stream>>>(x, xb, c0, Wfx, bf_, Wfh, Wix, bi_, Wih,
                                                Wox, bo_, Woh, Wcx, bc_, Wch, hbb, slots, out);
    } else if (ws_size >= need_ping) {
        short* hbb = (short*)(ws + off_hb_ping);
        short* xb  = (short*)(ws + off_xb_ping);
        convert_x_kernel<<<(Tn * Bn * Dn / 8) / 256, 256, 0, stream>>>(x, xb);
        prep_kernel<<<256, 256, 0, stream>>>(h0, hbb, slots);
        lstm_kernel<1><<<256, 256, 0, stream>>>(x, xb, c0, Wfx, bf_, Wfh, Wix, bi_, Wih,
                                                Wox, bo_, Woh, Wcx, bc_, Wch, hbb, slots, out);
    } else {
        short* hbb = (short*)(ws + off_hb_ping);
        prep_kernel<<<256, 256, 0, stream>>>(h0, hbb, slots);
        lstm_kernel<2><<<256, 256, 0, stream>>>(x, (const short*)nullptr, c0, Wfx, bf_, Wfh,
                                                Wix, bi_, Wih, Wox, bo_, Woh, Wcx, bc_, Wch,
                                                hbb, slots, out);
    }
}

// Round 4
// 3442.188 us; speedup vs baseline: 1.7843x; 1.7843x over previous
//
#include <hip/hip_runtime.h>
#include <cstdint>
#include <cmath>

#define Bn 64
#define Tn 512
#define Dn 1024
#define Hn 1024

typedef __attribute__((ext_vector_type(8))) short short8;
typedef __attribute__((ext_vector_type(8))) __bf16 bf16x8;
typedef __attribute__((ext_vector_type(16))) float floatx16;
typedef __attribute__((ext_vector_type(2))) unsigned long long ull2;

__device__ __forceinline__ short f2bf(float f) {
    unsigned u = __float_as_uint(f);
    unsigned r = (u + 0x7FFFu + ((u >> 16) & 1u)) >> 16;
    return (short)(r & 0xFFFFu);
}

// Cache-bypassing (system-scope) poll load pair: reads serve from MALL, never
// from a stale local L1/L2 line. sc0 sc1 = system scope on gfx950 MUBUF/FLAT.
__device__ __forceinline__ void poll_load2(const unsigned* p0, const unsigned* p1,
                                           unsigned& v0, unsigned& v1) {
    asm volatile("global_load_dword %0, %2, off sc0 sc1\n\t"
                 "global_load_dword %1, %3, off sc0 sc1\n\t"
                 "s_waitcnt vmcnt(0)"
                 : "=v"(v0), "=v"(v1)
                 : "v"(p0), "v"(p1)
                 : "memory");
}

// Write-through (system-scope) store: data lands at MALL, not dirty-in-L2.
__device__ __forceinline__ void store_thru(unsigned* p, unsigned v) {
    asm volatile("global_store_dword %0, %1, off sc0 sc1"
                 :: "v"(p), "v"(v) : "memory");
}

__device__ __forceinline__ unsigned long long load_bypass64(const unsigned long long* p) {
    unsigned long long v;
    asm volatile("global_load_dwordx2 %0, %1, off sc0 sc1\n\t"
                 "s_waitcnt vmcnt(0)"
                 : "=v"(v) : "v"(p) : "memory");
    return v;
}

// Convert x [B][T][D] fp32 -> xb [T][B][D] bf16 (time-major for per-step locality)
__global__ void convert_x_kernel(const float* __restrict__ x, short* __restrict__ xb) {
    size_t idx = ((size_t)blockIdx.x * blockDim.x + threadIdx.x) * 8;
    size_t b = idx >> 19;              // T*D = 2^19
    size_t r = idx & ((1u << 19) - 1);
    size_t t = r >> 10;                // D = 2^10
    size_t d = r & 1023;
    const float* src = x + idx;
    short8 o;
#pragma unroll
    for (int j = 0; j < 8; ++j) o[j] = f2bf(src[j]);
    *(short8*)(xb + ((t * Bn + b) << 10) + d) = o;
}

// Init h buffer 0 from h0 (bf16) and zero the barrier slot array (64 KB)
__global__ void prep_kernel(const float* __restrict__ h0, short* __restrict__ hb,
                            unsigned* __restrict__ slots) {
    int i = blockIdx.x * blockDim.x + threadIdx.x;   // 0..65535
    hb[i] = f2bf(h0[i]);                              // B*H = 65536
    if (i < 16384) slots[i] = 0;                      // 2 groups * 128 slots * 64 u32
}

// MODE 0: full per-step h buffers (never-reused lines -> plain cached reads) + bf16 x
// MODE 1: ping-pong h buffers, bypassing h reads + bf16 x
// MODE 2: like 1 but x read as fp32 directly (tiny-ws fallback)
template <int MODE>
__global__ __launch_bounds__(256, 1)
void lstm_kernel(const float* __restrict__ x, const short* __restrict__ xb,
                 const float* __restrict__ c0,
                 const float* __restrict__ Wfx, const float* __restrict__ bf_, const float* __restrict__ Wfh,
                 const float* __restrict__ Wix, const float* __restrict__ bi_, const float* __restrict__ Wih,
                 const float* __restrict__ Wox, const float* __restrict__ bo_, const float* __restrict__ Woh,
                 const float* __restrict__ Wcx, const float* __restrict__ bc_, const float* __restrict__ Wch,
                 short* __restrict__ hbb, unsigned* __restrict__ slots,
                 float* __restrict__ out) {
    constexpr bool FULL = (MODE == 0);
    constexpr bool XB = (MODE <= 1);
    // WS=2066 shorts -> 1033 dwords = 9 (mod 32): b128 weight reads are 2-way (free)
    constexpr int WS = 2066;
    constexpr int BH = Bn * Hn;              // 65536 shorts per h buffer
    __shared__ short Wlds[32 * WS];          // 132224 B
    __shared__ float Gs[4][32][33];          // 16896 B: [wave][col][row(batch)]

    const int tid = threadIdx.x;
    const int blk = blockIdx.x;
    const int group = blk >> 7;              // 0..1 (32 batches each)
    const int bIG = blk & 127;               // block in group
    const int u0 = bIG * 8;                  // 8 hidden units per block

    // ---- stage weight slices into LDS (fp32 global -> bf16 LDS) ----
    {
        const int col = tid & 31;            // 0..31 = gate*8 + u
        const int kr0 = tid >> 5;            // 0..7
        const int gate = col >> 3;
        const int uu = col & 7;
        const float* Wxm = (gate == 0) ? Wfx : (gate == 1) ? Wix : (gate == 2) ? Wox : Wcx;
        const float* Whm = (gate == 0) ? Wfh : (gate == 1) ? Wih : (gate == 2) ? Woh : Wch;
        for (int k = kr0; k < 1024; k += 8) {
            Wlds[col * WS + k]        = f2bf(Wxm[(size_t)k * Hn + u0 + uu]);
            Wlds[col * WS + 1024 + k] = f2bf(Whm[(size_t)k * Hn + u0 + uu]);
        }
    }

    // ---- epilogue-role state: thread owns (batch b_loc, unit uu2) ----
    const int b_loc = tid >> 3;              // 0..31
    const int uu2 = tid & 7;                 // 0..7
    const int bglob_e = group * 32 + b_loc;
    float c_state = c0[(size_t)bglob_e * Hn + u0 + uu2];
    const float bfv = bf_[u0 + uu2], biv = bi_[u0 + uu2];
    const float bov = bo_[u0 + uu2], bcv = bc_[u0 + uu2];
    float* outp = out + (size_t)bglob_e * Tn * Hn + u0 + uu2;

    // ---- MFMA-role constants: wave w covers K-slice [w*512, w*512+512) of (x|h) ----
    const int w = tid >> 6;
    const int lane = tid & 63;
    const int nm = lane & 31;                // m (batch) for A, n (col) for B
    const int half = lane >> 5;              // k sub-block
    const int src = w >> 1;                  // 0 = x, 1 = h
    const int kh = w & 1;                    // k-half within source
    const short* bfrag_base = &Wlds[nm * WS + src * 1024 + kh * 512 + half * 8];
    const int kofs = kh * 512 + half * 8;
    const int bglob_a = group * 32 + nm;

    unsigned* myslots = slots + group * 128 * 64;  // 256B-spaced slots
    unsigned* myslot = myslots + bIG * 64;

    // x A-fragments live in registers across the barrier (pipelined prefetch)
    bf16x8 afrag[32];
    if (XB && src == 0) {
        const short* A0 = xb + (((size_t)0 * Bn + bglob_a) << 10) + kofs;
#pragma unroll
        for (int j = 0; j < 32; ++j) afrag[j] = *(const bf16x8*)(const void*)(A0 + j * 16);
    }

    __syncthreads();

    for (int t = 0; t < Tn; ++t) {
        // ---- h-wave-only poll with cache-bypassing loads (read from MALL) ----
        if (src == 1 && t > 0) {
            const unsigned* p0 = myslots + (size_t)lane * 64;
            const unsigned* p1 = myslots + (size_t)(lane + 64) * 64;
            for (;;) {
                unsigned v0, v1;
                poll_load2(p0, p1, v0, v1);
                if (__all((v0 >= (unsigned)t) && (v1 >= (unsigned)t))) break;
            }
        }

        floatx16 acc0, acc1;
#pragma unroll
        for (int r_ = 0; r_ < 16; ++r_) { acc0[r_] = 0.f; acc1[r_] = 0.f; }

        if (XB && src == 0) {
#pragma unroll
            for (int j = 0; j < 32; j += 2) {
                bf16x8 b0 = *(const bf16x8*)(const void*)(bfrag_base + j * 16);
                bf16x8 b1 = *(const bf16x8*)(const void*)(bfrag_base + j * 16 + 16);
                acc0 = __builtin_amdgcn_mfma_f32_32x32x16_bf16(afrag[j], b0, acc0, 0, 0, 0);
                acc1 = __builtin_amdgcn_mfma_f32_32x32x16_bf16(afrag[j + 1], b1, acc1, 0, 0, 0);
            }
        } else if (src == 1) {
            if (FULL) {
                // buffer t holds h(t); lines are fresh (never read before) ->
                // plain cached loads must miss to MALL where sc1 stores landed
                const short* Ab = hbb + (size_t)t * BH + ((size_t)bglob_a << 10) + kofs;
#pragma unroll
                for (int j = 0; j < 32; j += 2) {
                    bf16x8 a0 = *(const bf16x8*)(const void*)(Ab + j * 16);
                    bf16x8 b0 = *(const bf16x8*)(const void*)(bfrag_base + j * 16);
                    bf16x8 a1 = *(const bf16x8*)(const void*)(Ab + j * 16 + 16);
                    bf16x8 b1 = *(const bf16x8*)(const void*)(bfrag_base + j * 16 + 16);
                    acc0 = __builtin_amdgcn_mfma_f32_32x32x16_bf16(a0, b0, acc0, 0, 0, 0);
                    acc1 = __builtin_amdgcn_mfma_f32_32x32x16_bf16(a1, b1, acc1, 0, 0, 0);
                }
            } else {
                const unsigned long long* Ab64 = (const unsigned long long*)
                    (hbb + (size_t)(t & 1) * BH + ((size_t)bglob_a << 10) + kofs);
#pragma unroll
                for (int j = 0; j < 32; ++j) {
                    ull2 q;
                    q[0] = load_bypass64(Ab64 + j * 4);
                    q[1] = load_bypass64(Ab64 + j * 4 + 1);
                    bf16x8 a = __builtin_bit_cast(bf16x8, q);
                    bf16x8 b0 = *(const bf16x8*)(const void*)(bfrag_base + j * 16);
                    if (j & 1) acc1 = __builtin_amdgcn_mfma_f32_32x32x16_bf16(a, b0, acc1, 0, 0, 0);
                    else       acc0 = __builtin_amdgcn_mfma_f32_32x32x16_bf16(a, b0, acc0, 0, 0, 0);
                }
            }
        } else {
            // MODE2: read fp32 x directly and convert in-register
            const float* Af = x + ((size_t)bglob_a * Tn + t) * Dn + kofs;
#pragma unroll
            for (int ks = 0; ks < 32; ++ks) {
                short8 tmp;
#pragma unroll
                for (int j = 0; j < 8; ++j) tmp[j] = f2bf(Af[ks * 16 + j]);
                bf16x8 a = __builtin_bit_cast(bf16x8, tmp);
                bf16x8 b0 = *(const bf16x8*)(const void*)(bfrag_base + ks * 16);
                if (ks & 1) acc1 = __builtin_amdgcn_mfma_f32_32x32x16_bf16(a, b0, acc1, 0, 0, 0);
                else        acc0 = __builtin_amdgcn_mfma_f32_32x32x16_bf16(a, b0, acc0, 0, 0, 0);
            }
        }

        // write partial sums: C/D layout col=lane&31, row=(reg&3)+8*(reg>>2)+4*(lane>>5)
#pragma unroll
        for (int r_ = 0; r_ < 16; ++r_) {
            int row = (r_ & 3) + 8 * (r_ >> 2) + 4 * half;
            Gs[w][nm][row] = acc0[r_] + acc1[r_];
        }
        __syncthreads();   // sync1: Gs write -> read

        // ---- epilogue: gates in fp32 ----
        float zf = Gs[0][uu2][b_loc] + Gs[1][uu2][b_loc] + Gs[2][uu2][b_loc] + Gs[3][uu2][b_loc] + bfv;
        float zi = Gs[0][8 + uu2][b_loc] + Gs[1][8 + uu2][b_loc] + Gs[2][8 + uu2][b_loc] + Gs[3][8 + uu2][b_loc] + biv;
        float zo = Gs[0][16 + uu2][b_loc] + Gs[1][16 + uu2][b_loc] + Gs[2][16 + uu2][b_loc] + Gs[3][16 + uu2][b_loc] + bov;
        float zc = Gs[0][24 + uu2][b_loc] + Gs[1][24 + uu2][b_loc] + Gs[2][24 + uu2][b_loc] + Gs[3][24 + uu2][b_loc] + bcv;
        float fg = fminf(fmaxf(fmaf(0.2f, zf, 0.5f), 0.f), 1.f);
        float ig = fminf(fmaxf(fmaf(0.2f, zi, 0.5f), 0.f), 1.f);
        float og = fminf(fmaxf(fmaf(0.2f, zo, 0.5f), 0.f), 1.f);
        float ct = tanhf(zc);
        c_state = fg * c_state + ig * ct;
        float hv = og * tanhf(c_state);

        // ---- h store FIRST, write-through to MALL ----
        {
            unsigned hv32 = (unsigned short)f2bf(hv);
            unsigned part = (unsigned)__shfl_xor((int)hv32, 1);
            if (!(tid & 1)) {
                unsigned packed = hv32 | (part << 16);
                size_t bofs = FULL ? (size_t)(t + 1) * BH : (size_t)((t + 1) & 1) * BH;
                store_thru((unsigned*)(hbb + bofs + ((size_t)bglob_e << 10) + u0 + uu2), packed);
            }
        }

        __syncthreads();   // sync2: per-wave vmcnt(0) -> all h stores acked at MALL

        // ---- release: write-through flag; data is already at MALL ----
        if (t < Tn - 1 && tid == 0)
            store_thru(myslot, (unsigned)(t + 1));

        outp[(size_t)t * Hn] = hv;   // out store overlaps next step

        // next-step x fragments: loads stay in flight while h-waves spin
        if (XB && src == 0 && t < Tn - 1) {
            const short* An = xb + (((size_t)(t + 1) * Bn + bglob_a) << 10) + kofs;
#pragma unroll
            for (int j = 0; j < 32; ++j) afrag[j] = *(const bf16x8*)(const void*)(An + j * 16);
        }
    }
}

extern "C" void kernel_launch(void* const* d_in, const int* in_sizes, int n_in,
                              void* d_out, int out_size, void* d_ws, size_t ws_size,
                              hipStream_t stream) {
    const float* x   = (const float*)d_in[0];
    const float* c0  = (const float*)d_in[1];
    const float* h0  = (const float*)d_in[2];
    const float* Wfx = (const float*)d_in[3];
    const float* bf_ = (const float*)d_in[4];
    const float* Wfh = (const float*)d_in[5];
    const float* Wix = (const float*)d_in[6];
    const float* bi_ = (const float*)d_in[7];
    const float* Wih = (const float*)d_in[8];
    const float* Wox = (const float*)d_in[9];
    const float* bo_ = (const float*)d_in[10];
    const float* Woh = (const float*)d_in[11];
    const float* Wcx = (const float*)d_in[12];
    const float* bc_ = (const float*)d_in[13];
    const float* Wch = (const float*)d_in[14];
    (void)in_sizes; (void)n_in; (void)out_size;
    float* out = (float*)d_out;

    char* ws = (char*)d_ws;
    unsigned* slots = (unsigned*)ws;                         // [0, 64 KB)
    const size_t xb_bytes = (size_t)Tn * Bn * Dn * 2;        // 64 MB

    const size_t off_hb = 1u << 20;                          // 1 MB
    const size_t off_xb_full = (70u << 20);
    const size_t need_full = off_xb_full + xb_bytes;         // ~134 MB
    const size_t off_xb_ping = 1u << 20;
    const size_t off_hb_ping = 64u << 10;
    const size_t need_ping = off_xb_ping + xb_bytes;         // ~65 MB

    if (ws_size >= need_full) {
        short* hbb = (short*)(ws + off_hb);
        short* xb  = (short*)(ws + off_xb_full);
        convert_x_kernel<<<(Tn * Bn * Dn / 8) / 256, 256, 0, stream>>>(x, xb);
        prep_kernel<<<256, 256, 0, stream>>>(h0, hbb, slots);
        lstm_kernel<0><<<256, 256, 0, stream>>>(x, xb, c0, Wfx, bf_, Wfh, Wix, bi_, Wih,
                                                Wox, bo_, Woh, Wcx, bc_, Wch, hbb, slots, out);
    } else if (ws_size >= need_ping) {
        short* hbb = (short*)(ws + off_hb_ping);
        short* xb  = (short*)(ws + off_xb_ping);
        convert_x_kernel<<<(Tn * Bn * Dn / 8) / 256, 256, 0, stream>>>(x, xb);
        prep_kernel<<<256, 256, 0, stream>>>(h0, hbb, slots);
        lstm_kernel<1><<<256, 256, 0, stream>>>(x, xb, c0, Wfx, bf_, Wfh, Wix, bi_, Wih,
                                                Wox, bo_, Woh, Wcx, bc_, Wch, hbb, slots, out);
    } else {
        short* hbb = (short*)(ws + off_hb_ping);
        prep_kernel<<<256, 256, 0, stream>>>(h0, hbb, slots);
        lstm_kernel<2><<<256, 256, 0, stream>>>(x, (const short*)nullptr, c0, Wfx, bf_, Wfh,
                                                Wix, bi_, Wih, Wox, bo_, Woh, Wcx, bc_, Wch,
                                                hbb, slots, out);
    }
}